// Round 2
// baseline (524.277 us; speedup 1.0000x reference)
//
#include <hip/hip_runtime.h>

// ---------------------------------------------------------------------------
// ResNet sparse-conv block, round 2: barrier-free gather-to-register MFMA.
//   wprep        : pack W1,W2 as bf16 MFMA B-fragments [k][fi][lane][8]; zero stats
//   channel_stats: per-channel sum/sumsq of x
//   bn_relu_f32  : h1 = bf16(relu(bn1(x)))
//   spconv       : out1(bf16) = sum_k gather(h1) @ W1[k], fused stats, LDS-transposed epilogue
//   bn_relu_b16  : h2 = bf16(relu(bn2(out1)))
//   spconv       : out(fp32) = sum_k gather(h2) @ W2[k] + x
// ---------------------------------------------------------------------------

#define KOFF 27

typedef __bf16 bf16x8 __attribute__((ext_vector_type(8)));
typedef float floatx4 __attribute__((ext_vector_type(4)));

__device__ __forceinline__ unsigned short f2bf(float x) {
    union { float f; unsigned int u; } v; v.f = x;
    unsigned int u = v.u;
    unsigned int r = u + 0x7FFFu + ((u >> 16) & 1u);
    return (unsigned short)(r >> 16);
}
__device__ __forceinline__ float bf2f(unsigned short s) {
    union { float f; unsigned int u; } v; v.u = ((unsigned int)s) << 16; return v.f;
}

// --- prep: W -> bf16 fragments Wf[k][fi=ct*2+ks][lane][j]; zero stats -------
// element j of frag (ct,ks) for lane (q,l15) = W[k][cin=ks*32+q*8+j][cout=ct*16+l15]
__global__ void wprep(const float* __restrict__ W1, const float* __restrict__ W2,
                      unsigned short* __restrict__ W1f, unsigned short* __restrict__ W2f,
                      float* __restrict__ stats) {
    int tt = blockIdx.x * 256 + threadIdx.x;          // 864*256 = 221184 exactly
    if (blockIdx.x == 0) { stats[threadIdx.x] = 0.f; stats[256 + threadIdx.x] = 0.f; }
    const float* src; unsigned short* dst; int e;
    if (tt < 110592) { src = W1; dst = W1f; e = tt; }
    else             { src = W2; dst = W2f; e = tt - 110592; }
    int j = e & 7, lane = (e >> 3) & 63, fi = (e >> 9) & 7, k = e >> 12;
    int ct = fi >> 1, ks = fi & 1, q = lane >> 4, l15 = lane & 15;
    int cin = ks * 32 + q * 8 + j, cout = ct * 16 + l15;
    dst[e] = f2bf(src[k * 4096 + cin * 64 + cout]);
}

// --- per-channel sum / sumsq ------------------------------------------------
__global__ void channel_stats(const float* __restrict__ in, float* __restrict__ stats,
                              int total) {
    __shared__ float s[128];
    int t = threadIdx.x;
    if (t < 128) s[t] = 0.f;
    __syncthreads();
    int i = blockIdx.x * blockDim.x + t;
    int stride = gridDim.x * blockDim.x;   // multiple of 64
    int c = i & 63;
    float s1 = 0.f, s2 = 0.f;
    for (; i < total; i += stride) { float v = in[i]; s1 += v; s2 += v * v; }
    atomicAdd(&s[c], s1);
    atomicAdd(&s[64 + c], s2);
    __syncthreads();
    if (t < 64) { atomicAdd(&stats[t], s[t]); atomicAdd(&stats[64 + t], s[64 + t]); }
}

// --- BN + ReLU + bf16 cast, fp32 input --------------------------------------
__global__ void bn_relu_f32(const float* __restrict__ in, const float* __restrict__ sums,
                            const float* __restrict__ gamma, const float* __restrict__ beta,
                            unsigned short* __restrict__ out, int total4, float invN) {
    __shared__ float sab[128];
    int t = threadIdx.x;
    if (t < 64) {
        float mu  = sums[t] * invN;
        float var = fmaxf(sums[64 + t] * invN - mu * mu, 0.f);
        float a   = gamma[t] * rsqrtf(var + 1e-5f);
        sab[t] = a; sab[64 + t] = beta[t] - mu * a;
    }
    __syncthreads();
    int i = blockIdx.x * blockDim.x + t;
    int stride = gridDim.x * blockDim.x;
    for (; i < total4; i += stride) {
        float4 v = ((const float4*)in)[i];
        int c0 = (i << 2) & 63;
        ushort4 o;
        o.x = f2bf(fmaxf(sab[c0]     * v.x + sab[64 + c0],     0.f));
        o.y = f2bf(fmaxf(sab[c0 + 1] * v.y + sab[64 + c0 + 1], 0.f));
        o.z = f2bf(fmaxf(sab[c0 + 2] * v.z + sab[64 + c0 + 2], 0.f));
        o.w = f2bf(fmaxf(sab[c0 + 3] * v.w + sab[64 + c0 + 3], 0.f));
        ((ushort4*)out)[i] = o;
    }
}

// --- BN + ReLU + bf16 cast, bf16 input --------------------------------------
__global__ void bn_relu_b16(const unsigned short* __restrict__ in, const float* __restrict__ sums,
                            const float* __restrict__ gamma, const float* __restrict__ beta,
                            unsigned short* __restrict__ out, int total8, float invN) {
    __shared__ float sab[128];
    int t = threadIdx.x;
    if (t < 64) {
        float mu  = sums[t] * invN;
        float var = fmaxf(sums[64 + t] * invN - mu * mu, 0.f);
        float a   = gamma[t] * rsqrtf(var + 1e-5f);
        sab[t] = a; sab[64 + t] = beta[t] - mu * a;
    }
    __syncthreads();
    int i = blockIdx.x * blockDim.x + t;
    int stride = gridDim.x * blockDim.x;
    for (; i < total8; i += stride) {
        uint4 v = ((const uint4*)in)[i];
        int c0 = (i << 3) & 63;
        unsigned int w[4] = {v.x, v.y, v.z, v.w};
        unsigned int o[4];
        #pragma unroll
        for (int p = 0; p < 4; ++p) {
            float f0 = bf2f((unsigned short)(w[p] & 0xffff));
            float f1 = bf2f((unsigned short)(w[p] >> 16));
            int c = c0 + p * 2;
            unsigned short r0 = f2bf(fmaxf(sab[c]     * f0 + sab[64 + c],     0.f));
            unsigned short r1 = f2bf(fmaxf(sab[c + 1] * f1 + sab[64 + c + 1], 0.f));
            o[p] = (unsigned int)r0 | ((unsigned int)r1 << 16);
        }
        ((uint4*)out)[i] = make_uint4(o[0], o[1], o[2], o[3]);
    }
}

#define MFMA(a, b, c) __builtin_amdgcn_mfma_f32_16x16x32_bf16(a, b, c, 0, 0, 0)

// --- barrier-free gather->register MFMA sparse conv -------------------------
// Block 256 thr (4 waves), 128 output rows. Wave wid owns rows wid*32..+32
// (two 16-row m-tiles). A-frag gathered straight from global: lane reads 16B
// at h[g]*128B + (ks*4+q)*16. B-frags from packed Wf (coalesced, L1/L2-hot).
// No LDS in the K-loop, no barriers -> pure TLP latency hiding.
__global__ __launch_bounds__(256, 4) void spconv(
        const unsigned short* __restrict__ h,     // [N,64] bf16
        const int* __restrict__ idx,              // [N,27]
        const unsigned short* __restrict__ Wf,    // packed frags
        unsigned short* __restrict__ outb,        // conv1 out (bf16) or null
        float* __restrict__ outf,                 // conv2 out (fp32) or null
        const float* __restrict__ resid,          // conv2 residual or null
        float* __restrict__ stats,                // conv1 fused stats or null
        int N) {
    __shared__ float sE[128 * 68];                // +4 pad: 2-way banks (free)
    __shared__ float sred[128];
    int t = threadIdx.x, lane = t & 63, wid = t >> 6;
    int q = lane >> 4, l15 = lane & 15;
    int base = blockIdx.x * 128;
    if (t < 128) sred[t] = 0.f;
    __syncthreads();

    int r0 = base + wid * 32 + l15;
    int r1 = r0 + 16;
    const int* ip0 = idx + (size_t)min(r0, N - 1) * KOFF;
    const int* ip1 = idx + (size_t)min(r1, N - 1) * KOFF;

    floatx4 acc[2][4];
    #pragma unroll
    for (int a_ = 0; a_ < 2; ++a_)
        #pragma unroll
        for (int b_ = 0; b_ < 4; ++b_)
            acc[a_][b_] = floatx4{0.f, 0.f, 0.f, 0.f};

    int qo = q * 8;                              // element offset of quad chunk
    int g0 = ip0[0], g1 = ip1[0];
    bf16x8 a00 = *(const bf16x8*)(h + ((size_t)g0 << 6) + qo);
    bf16x8 a01 = *(const bf16x8*)(h + ((size_t)g0 << 6) + 32 + qo);
    bf16x8 a10 = *(const bf16x8*)(h + ((size_t)g1 << 6) + qo);
    bf16x8 a11 = *(const bf16x8*)(h + ((size_t)g1 << 6) + 32 + qo);
    int g0n = ip0[1], g1n = ip1[1];

    #pragma unroll 1
    for (int k = 0; k < KOFF; ++k) {
        // B-frags for k first (MFMA's vmcnt wait covers only these)
        const unsigned short* wp = Wf + (size_t)k * 4096 + (size_t)lane * 8;
        bf16x8 b00 = *(const bf16x8*)(wp);
        bf16x8 b01 = *(const bf16x8*)(wp + 512);
        bf16x8 b10 = *(const bf16x8*)(wp + 1024);
        bf16x8 b11 = *(const bf16x8*)(wp + 1536);
        bf16x8 b20 = *(const bf16x8*)(wp + 2048);
        bf16x8 b21 = *(const bf16x8*)(wp + 2560);
        bf16x8 b30 = *(const bf16x8*)(wp + 3072);
        bf16x8 b31 = *(const bf16x8*)(wp + 3584);
        // prefetch A-frags for k+1 (latency overlaps this k's MFMAs)
        bf16x8 n00 = *(const bf16x8*)(h + ((size_t)g0n << 6) + qo);
        bf16x8 n01 = *(const bf16x8*)(h + ((size_t)g0n << 6) + 32 + qo);
        bf16x8 n10 = *(const bf16x8*)(h + ((size_t)g1n << 6) + qo);
        bf16x8 n11 = *(const bf16x8*)(h + ((size_t)g1n << 6) + 32 + qo);
        // prefetch indices for k+2
        int k2 = (k + 2 < KOFF) ? (k + 2) : (KOFF - 1);
        int t0 = ip0[k2], t1 = ip1[k2];

        acc[0][0] = MFMA(a00, b00, acc[0][0]); acc[0][0] = MFMA(a01, b01, acc[0][0]);
        acc[0][1] = MFMA(a00, b10, acc[0][1]); acc[0][1] = MFMA(a01, b11, acc[0][1]);
        acc[0][2] = MFMA(a00, b20, acc[0][2]); acc[0][2] = MFMA(a01, b21, acc[0][2]);
        acc[0][3] = MFMA(a00, b30, acc[0][3]); acc[0][3] = MFMA(a01, b31, acc[0][3]);
        acc[1][0] = MFMA(a10, b00, acc[1][0]); acc[1][0] = MFMA(a11, b01, acc[1][0]);
        acc[1][1] = MFMA(a10, b10, acc[1][1]); acc[1][1] = MFMA(a11, b11, acc[1][1]);
        acc[1][2] = MFMA(a10, b20, acc[1][2]); acc[1][2] = MFMA(a11, b21, acc[1][2]);
        acc[1][3] = MFMA(a10, b30, acc[1][3]); acc[1][3] = MFMA(a11, b31, acc[1][3]);

        a00 = n00; a01 = n01; a10 = n10; a11 = n11;
        g0n = t0; g1n = t1;
    }

    // fused stats of this conv's output (conv1): mask tail rows
    if (stats) {
        #pragma unroll
        for (int ct = 0; ct < 4; ++ct) {
            float s1 = 0.f, s2 = 0.f;
            #pragma unroll
            for (int rt = 0; rt < 2; ++rt)
                #pragma unroll
                for (int r = 0; r < 4; ++r) {
                    int rowc = base + wid * 32 + rt * 16 + q * 4 + r;
                    float vv = (rowc < N) ? acc[rt][ct][r] : 0.f;
                    s1 += vv; s2 += vv * vv;
                }
            s1 += __shfl_xor(s1, 16); s2 += __shfl_xor(s2, 16);
            s1 += __shfl_xor(s1, 32); s2 += __shfl_xor(s2, 32);
            if (q == 0) {
                atomicAdd(&sred[ct * 16 + l15], s1);
                atomicAdd(&sred[64 + ct * 16 + l15], s2);
            }
        }
    }

    // transpose through LDS -> full-line coalesced stores
    #pragma unroll
    for (int rt = 0; rt < 2; ++rt)
        #pragma unroll
        for (int ct = 0; ct < 4; ++ct)
            #pragma unroll
            for (int r = 0; r < 4; ++r)
                sE[(wid * 32 + rt * 16 + q * 4 + r) * 68 + ct * 16 + l15] = acc[rt][ct][r];
    __syncthreads();
    if (stats && t < 64) {
        atomicAdd(&stats[t], sred[t]);
        atomicAdd(&stats[64 + t], sred[64 + t]);
    }

    int row = t >> 1, half = t & 1;
    int grow = base + row;
    if (grow < N) {
        const float* sp = sE + row * 68 + half * 32;
        if (outb) {
            unsigned short* op = outb + ((size_t)grow << 6) + half * 32;
            #pragma unroll
            for (int j = 0; j < 8; ++j) {
                float4 v = *(const float4*)(sp + j * 4);
                ushort4 o = { f2bf(v.x), f2bf(v.y), f2bf(v.z), f2bf(v.w) };
                *(ushort4*)(op + j * 4) = o;
            }
        } else {
            const float* rp = resid + ((size_t)grow << 6) + half * 32;
            float* op = outf + ((size_t)grow << 6) + half * 32;
            #pragma unroll
            for (int j = 0; j < 8; ++j) {
                float4 v = *(const float4*)(sp + j * 4);
                float4 rv = *(const float4*)(rp + j * 4);
                v.x += rv.x; v.y += rv.y; v.z += rv.z; v.w += rv.w;
                *(float4*)(op + j * 4) = v;
            }
        }
    }
}

// ---------------------------------------------------------------------------
extern "C" void kernel_launch(void* const* d_in, const int* in_sizes, int n_in,
                              void* d_out, int out_size, void* d_ws, size_t ws_size,
                              hipStream_t stream) {
    const float* x      = (const float*)d_in[0];
    const int*   nbr    = (const int*)  d_in[1];
    const float* W1     = (const float*)d_in[2];
    const float* gamma1 = (const float*)d_in[3];
    const float* beta1  = (const float*)d_in[4];
    const float* W2     = (const float*)d_in[5];
    const float* gamma2 = (const float*)d_in[6];
    const float* beta2  = (const float*)d_in[7];
    float* out = (float*)d_out;

    int N = in_sizes[0] / 64;
    float invN = 1.0f / (float)N;

    // workspace layout (16B-aligned chunks)
    char* ws = (char*)d_ws;
    float*          stats = (float*)ws;                           // 512 floats
    unsigned short* W1f   = (unsigned short*)(ws + 4096);         // 110592 bf16
    unsigned short* W2f   = W1f + 110592;
    unsigned short* hbuf  = W2f + 110592;                         // [N,64] bf16
    unsigned short* out1b = hbuf + (size_t)N * 64;                // [N,64] bf16

    int nb = (N + 127) / 128;

    wprep<<<864, 256, 0, stream>>>(W1, W2, W1f, W2f, stats);
    channel_stats<<<640, 256, 0, stream>>>(x, stats, N * 64);
    bn_relu_f32<<<768, 256, 0, stream>>>(x, stats, gamma1, beta1, hbuf, N * 16, invN);
    spconv<<<nb, 256, 0, stream>>>(hbuf, nbr, W1f, out1b, nullptr, nullptr, stats + 256, N);
    bn_relu_b16<<<768, 256, 0, stream>>>(out1b, stats + 256, gamma2, beta2, hbuf, N * 8, invN);
    spconv<<<nb, 256, 0, stream>>>(hbuf, nbr, W2f, nullptr, out, x, nullptr, N);
}

// Round 3
// 499.679 us; speedup vs baseline: 1.0492x; 1.0492x over previous
//
#include <hip/hip_runtime.h>

// ---------------------------------------------------------------------------
// ResNet sparse-conv block, round 3: depth-2 gather pipeline, slim LDS.
//   memset        : zero stats (512 floats)
//   prep_stats    : blocks<864 pack W1,W2 bf16 B-fragments; rest: stats of x
//   bn_relu_f32   : h1 = bf16(relu(bn1(x)))
//   spconv        : out1(bf16) = sum_k gather(h1) @ W1[k], fused stats
//   bn_relu_b16   : h2 = bf16(relu(bn2(out1)))
//   spconv        : out(fp32) = sum_k gather(h2) @ W2[k] + x
// ---------------------------------------------------------------------------

#define KOFF 27

typedef __bf16 bf16x8 __attribute__((ext_vector_type(8)));
typedef float floatx4 __attribute__((ext_vector_type(4)));

__device__ __forceinline__ unsigned short f2bf(float x) {
    union { float f; unsigned int u; } v; v.f = x;
    unsigned int u = v.u;
    unsigned int r = u + 0x7FFFu + ((u >> 16) & 1u);
    return (unsigned short)(r >> 16);
}
__device__ __forceinline__ float bf2f(unsigned short s) {
    union { float f; unsigned int u; } v; v.u = ((unsigned int)s) << 16; return v.f;
}

// --- fused: W -> bf16 fragment pack  |  per-channel stats of x --------------
// frag element j of (ct,ks) for lane (q,l15) = W[k][cin=ks*32+q*8+j][cout=ct*16+l15]
__global__ void prep_stats(const float* __restrict__ W1, const float* __restrict__ W2,
                           unsigned short* __restrict__ W1f, unsigned short* __restrict__ W2f,
                           const float* __restrict__ x, float* __restrict__ stats,
                           int total) {
    int b = blockIdx.x, t = threadIdx.x;
    if (b < 864) {                                  // 864*256 = 221184 = 2*110592
        int tt = b * 256 + t;
        const float* src; unsigned short* dst; int e;
        if (tt < 110592) { src = W1; dst = W1f; e = tt; }
        else             { src = W2; dst = W2f; e = tt - 110592; }
        int j = e & 7, lane = (e >> 3) & 63, fi = (e >> 9) & 7, k = e >> 12;
        int ct = fi >> 1, ks = fi & 1, q = lane >> 4, l15 = lane & 15;
        int cin = ks * 32 + q * 8 + j, cout = ct * 16 + l15;
        dst[e] = f2bf(src[k * 4096 + cin * 64 + cout]);
        return;
    }
    __shared__ float s[128];
    if (t < 128) s[t] = 0.f;
    __syncthreads();
    int i = (b - 864) * 256 + t;
    int stride = (gridDim.x - 864) * 256;           // multiple of 64
    int c = i & 63;
    float s1 = 0.f, s2 = 0.f;
    for (; i < total; i += stride) { float v = x[i]; s1 += v; s2 += v * v; }
    atomicAdd(&s[c], s1);
    atomicAdd(&s[64 + c], s2);
    __syncthreads();
    if (t < 64) { atomicAdd(&stats[t], s[t]); atomicAdd(&stats[64 + t], s[64 + t]); }
}

// --- BN + ReLU + bf16 cast, fp32 input --------------------------------------
__global__ void bn_relu_f32(const float* __restrict__ in, const float* __restrict__ sums,
                            const float* __restrict__ gamma, const float* __restrict__ beta,
                            unsigned short* __restrict__ out, int total4, float invN) {
    __shared__ float sab[128];
    int t = threadIdx.x;
    if (t < 64) {
        float mu  = sums[t] * invN;
        float var = fmaxf(sums[64 + t] * invN - mu * mu, 0.f);
        float a   = gamma[t] * rsqrtf(var + 1e-5f);
        sab[t] = a; sab[64 + t] = beta[t] - mu * a;
    }
    __syncthreads();
    int i = blockIdx.x * blockDim.x + t;
    int stride = gridDim.x * blockDim.x;
    for (; i < total4; i += stride) {
        float4 v = ((const float4*)in)[i];
        int c0 = (i << 2) & 63;
        ushort4 o;
        o.x = f2bf(fmaxf(sab[c0]     * v.x + sab[64 + c0],     0.f));
        o.y = f2bf(fmaxf(sab[c0 + 1] * v.y + sab[64 + c0 + 1], 0.f));
        o.z = f2bf(fmaxf(sab[c0 + 2] * v.z + sab[64 + c0 + 2], 0.f));
        o.w = f2bf(fmaxf(sab[c0 + 3] * v.w + sab[64 + c0 + 3], 0.f));
        ((ushort4*)out)[i] = o;
    }
}

// --- BN + ReLU + bf16 cast, bf16 input --------------------------------------
__global__ void bn_relu_b16(const unsigned short* __restrict__ in, const float* __restrict__ sums,
                            const float* __restrict__ gamma, const float* __restrict__ beta,
                            unsigned short* __restrict__ out, int total8, float invN) {
    __shared__ float sab[128];
    int t = threadIdx.x;
    if (t < 64) {
        float mu  = sums[t] * invN;
        float var = fmaxf(sums[64 + t] * invN - mu * mu, 0.f);
        float a   = gamma[t] * rsqrtf(var + 1e-5f);
        sab[t] = a; sab[64 + t] = beta[t] - mu * a;
    }
    __syncthreads();
    int i = blockIdx.x * blockDim.x + t;
    int stride = gridDim.x * blockDim.x;
    for (; i < total8; i += stride) {
        uint4 v = ((const uint4*)in)[i];
        int c0 = (i << 3) & 63;
        unsigned int w[4] = {v.x, v.y, v.z, v.w};
        unsigned int o[4];
        #pragma unroll
        for (int p = 0; p < 4; ++p) {
            float f0 = bf2f((unsigned short)(w[p] & 0xffff));
            float f1 = bf2f((unsigned short)(w[p] >> 16));
            int c = c0 + p * 2;
            unsigned short r0 = f2bf(fmaxf(sab[c]     * f0 + sab[64 + c],     0.f));
            unsigned short r1 = f2bf(fmaxf(sab[c + 1] * f1 + sab[64 + c + 1], 0.f));
            o[p] = (unsigned int)r0 | ((unsigned int)r1 << 16);
        }
        ((uint4*)out)[i] = make_uint4(o[0], o[1], o[2], o[3]);
    }
}

#define MFMA(a, b, c) __builtin_amdgcn_mfma_f32_16x16x32_bf16(a, b, c, 0, 0, 0)

// --- depth-2 pipelined gather->register MFMA sparse conv --------------------
// Wave owns 32 rows (two 16-row m-tiles). A-frags gathered from global two
// k-iterations ahead (3-stage register buffer): ~2 MFMA-groups (~400+ cyc)
// of latency slack per gather. B-frags from packed Wf (1KB coalesced, L2-hot)
// loaded at top of each k. vmcnt is in-order, so issue order is:
//   B(k) -> gathers(k+2) -> idx(k+3) -> MFMAs(k)
// MFMAs wait only for B(k); gathers stay in flight across iterations.
__global__ __launch_bounds__(256, 4) void spconv(
        const unsigned short* __restrict__ h,     // [N,64] bf16
        const int* __restrict__ idx,              // [N,27]
        const unsigned short* __restrict__ Wf,    // packed frags
        unsigned short* __restrict__ outb,        // conv1 out (bf16) or null
        float* __restrict__ outf,                 // conv2 out (fp32) or null
        const float* __restrict__ resid,          // conv2 residual or null
        float* __restrict__ stats,                // conv1 fused stats or null
        int N) {
    __shared__ float sE[64 * 68];                 // half-tile epilogue buffer
    __shared__ float sred[128];
    int t = threadIdx.x, lane = t & 63, wid = t >> 6;
    int q = lane >> 4, l15 = lane & 15;
    int base = blockIdx.x * 128;
    if (t < 128) sred[t] = 0.f;
    __syncthreads();

    int r0 = base + wid * 32 + l15;
    int r1 = r0 + 16;
    const int* ip0 = idx + (size_t)min(r0, N - 1) * KOFF;
    const int* ip1 = idx + (size_t)min(r1, N - 1) * KOFF;

    floatx4 acc[2][4];
    #pragma unroll
    for (int a_ = 0; a_ < 2; ++a_)
        #pragma unroll
        for (int b_ = 0; b_ < 4; ++b_)
            acc[a_][b_] = floatx4{0.f, 0.f, 0.f, 0.f};

    int qo = q * 8;
    bf16x8 A0[4], A1[4], A2[4];
    {   // prologue: stage k=0,1; indices for k=2
        int g0 = ip0[0], g1 = ip1[0];
        A0[0] = *(const bf16x8*)(h + ((size_t)g0 << 6) + qo);
        A0[1] = *(const bf16x8*)(h + ((size_t)g0 << 6) + 32 + qo);
        A0[2] = *(const bf16x8*)(h + ((size_t)g1 << 6) + qo);
        A0[3] = *(const bf16x8*)(h + ((size_t)g1 << 6) + 32 + qo);
        g0 = ip0[1]; g1 = ip1[1];
        A1[0] = *(const bf16x8*)(h + ((size_t)g0 << 6) + qo);
        A1[1] = *(const bf16x8*)(h + ((size_t)g0 << 6) + 32 + qo);
        A1[2] = *(const bf16x8*)(h + ((size_t)g1 << 6) + qo);
        A1[3] = *(const bf16x8*)(h + ((size_t)g1 << 6) + 32 + qo);
    }
    int gc0 = ip0[2], gc1 = ip1[2];

#define BODY(CUR, NXT, KK) { \
    const unsigned short* wp = Wf + (size_t)(KK) * 4096 + (size_t)lane * 8;   \
    bf16x8 b00 = *(const bf16x8*)(wp);                                        \
    bf16x8 b01 = *(const bf16x8*)(wp + 512);                                  \
    bf16x8 b10 = *(const bf16x8*)(wp + 1024);                                 \
    bf16x8 b11 = *(const bf16x8*)(wp + 1536);                                 \
    bf16x8 b20 = *(const bf16x8*)(wp + 2048);                                 \
    bf16x8 b21 = *(const bf16x8*)(wp + 2560);                                 \
    bf16x8 b30 = *(const bf16x8*)(wp + 3072);                                 \
    bf16x8 b31 = *(const bf16x8*)(wp + 3584);                                 \
    if ((KK) <= 24) {                                                         \
        NXT[0] = *(const bf16x8*)(h + ((size_t)gc0 << 6) + qo);               \
        NXT[1] = *(const bf16x8*)(h + ((size_t)gc0 << 6) + 32 + qo);          \
        NXT[2] = *(const bf16x8*)(h + ((size_t)gc1 << 6) + qo);               \
        NXT[3] = *(const bf16x8*)(h + ((size_t)gc1 << 6) + 32 + qo);          \
    }                                                                         \
    if ((KK) <= 23) { gc0 = ip0[(KK) + 3]; gc1 = ip1[(KK) + 3]; }             \
    acc[0][0] = MFMA(CUR[0], b00, acc[0][0]);                                 \
    acc[0][0] = MFMA(CUR[1], b01, acc[0][0]);                                 \
    acc[0][1] = MFMA(CUR[0], b10, acc[0][1]);                                 \
    acc[0][1] = MFMA(CUR[1], b11, acc[0][1]);                                 \
    acc[0][2] = MFMA(CUR[0], b20, acc[0][2]);                                 \
    acc[0][2] = MFMA(CUR[1], b21, acc[0][2]);                                 \
    acc[0][3] = MFMA(CUR[0], b30, acc[0][3]);                                 \
    acc[0][3] = MFMA(CUR[1], b31, acc[0][3]);                                 \
    acc[1][0] = MFMA(CUR[2], b00, acc[1][0]);                                 \
    acc[1][0] = MFMA(CUR[3], b01, acc[1][0]);                                 \
    acc[1][1] = MFMA(CUR[2], b10, acc[1][1]);                                 \
    acc[1][1] = MFMA(CUR[3], b11, acc[1][1]);                                 \
    acc[1][2] = MFMA(CUR[2], b20, acc[1][2]);                                 \
    acc[1][2] = MFMA(CUR[3], b21, acc[1][2]);                                 \
    acc[1][3] = MFMA(CUR[2], b30, acc[1][3]);                                 \
    acc[1][3] = MFMA(CUR[3], b31, acc[1][3]);                                 \
}

    #pragma unroll 1
    for (int kk = 0; kk < KOFF; kk += 3) {
        BODY(A0, A2, kk)
        BODY(A1, A0, kk + 1)
        BODY(A2, A1, kk + 2)
    }
#undef BODY

    // fused stats of conv1 output (tail rows masked; invalid rows excluded)
    if (stats) {
        #pragma unroll
        for (int ct = 0; ct < 4; ++ct) {
            float s1 = 0.f, s2 = 0.f;
            #pragma unroll
            for (int rt = 0; rt < 2; ++rt)
                #pragma unroll
                for (int r = 0; r < 4; ++r) {
                    int rowc = base + wid * 32 + rt * 16 + q * 4 + r;
                    float vv = (rowc < N) ? acc[rt][ct][r] : 0.f;
                    s1 += vv; s2 += vv * vv;
                }
            s1 += __shfl_xor(s1, 16); s2 += __shfl_xor(s2, 16);
            s1 += __shfl_xor(s1, 32); s2 += __shfl_xor(s2, 32);
            if (q == 0) {
                atomicAdd(&sred[ct * 16 + l15], s1);
                atomicAdd(&sred[64 + ct * 16 + l15], s2);
            }
        }
    }

    // epilogue: two 64-row halves through a half-size LDS buffer
    #pragma unroll
    for (int hf = 0; hf < 2; ++hf) {
        if ((wid >> 1) == hf) {
            int lrow0 = (wid & 1) * 32;
            #pragma unroll
            for (int rt = 0; rt < 2; ++rt)
                #pragma unroll
                for (int ct = 0; ct < 4; ++ct)
                    #pragma unroll
                    for (int r = 0; r < 4; ++r)
                        sE[(lrow0 + rt * 16 + q * 4 + r) * 68 + ct * 16 + l15] = acc[rt][ct][r];
        }
        __syncthreads();
        if (hf == 0 && stats && t < 64) {
            atomicAdd(&stats[t], sred[t]);
            atomicAdd(&stats[64 + t], sred[64 + t]);
        }
        int rr = t >> 2, cc = t & 3;
        int grow = base + hf * 64 + rr;
        if (grow < N) {
            const float* sp = sE + rr * 68 + cc * 16;
            if (outb) {
                float4 v0 = *(const float4*)(sp);
                float4 v1 = *(const float4*)(sp + 4);
                float4 v2 = *(const float4*)(sp + 8);
                float4 v3 = *(const float4*)(sp + 12);
                ushort4 o0 = { f2bf(v0.x), f2bf(v0.y), f2bf(v0.z), f2bf(v0.w) };
                ushort4 o1 = { f2bf(v1.x), f2bf(v1.y), f2bf(v1.z), f2bf(v1.w) };
                ushort4 o2 = { f2bf(v2.x), f2bf(v2.y), f2bf(v2.z), f2bf(v2.w) };
                ushort4 o3 = { f2bf(v3.x), f2bf(v3.y), f2bf(v3.z), f2bf(v3.w) };
                unsigned short* op = outb + ((size_t)grow << 6) + cc * 16;
                *(ushort4*)(op)      = o0;
                *(ushort4*)(op + 4)  = o1;
                *(ushort4*)(op + 8)  = o2;
                *(ushort4*)(op + 12) = o3;
            } else {
                const float* rp = resid + ((size_t)grow << 6) + cc * 16;
                float* op = outf + ((size_t)grow << 6) + cc * 16;
                #pragma unroll
                for (int j = 0; j < 4; ++j) {
                    float4 v = *(const float4*)(sp + j * 4);
                    float4 rv = *(const float4*)(rp + j * 4);
                    v.x += rv.x; v.y += rv.y; v.z += rv.z; v.w += rv.w;
                    *(float4*)(op + j * 4) = v;
                }
            }
        }
        if (hf == 0) __syncthreads();
    }
}

// ---------------------------------------------------------------------------
extern "C" void kernel_launch(void* const* d_in, const int* in_sizes, int n_in,
                              void* d_out, int out_size, void* d_ws, size_t ws_size,
                              hipStream_t stream) {
    const float* x      = (const float*)d_in[0];
    const int*   nbr    = (const int*)  d_in[1];
    const float* W1     = (const float*)d_in[2];
    const float* gamma1 = (const float*)d_in[3];
    const float* beta1  = (const float*)d_in[4];
    const float* W2     = (const float*)d_in[5];
    const float* gamma2 = (const float*)d_in[6];
    const float* beta2  = (const float*)d_in[7];
    float* out = (float*)d_out;

    int N = in_sizes[0] / 64;
    float invN = 1.0f / (float)N;

    char* ws = (char*)d_ws;
    float*          stats = (float*)ws;                           // 512 floats
    unsigned short* W1f   = (unsigned short*)(ws + 4096);         // 110592 bf16
    unsigned short* W2f   = W1f + 110592;
    unsigned short* hbuf  = W2f + 110592;                         // [N,64] bf16
    unsigned short* out1b = hbuf + (size_t)N * 64;                // [N,64] bf16

    int nb = (N + 127) / 128;

    hipMemsetAsync(stats, 0, 2048, stream);
    prep_stats<<<864 + 512, 256, 0, stream>>>(W1, W2, W1f, W2f, x, stats, N * 64);
    bn_relu_f32<<<768, 256, 0, stream>>>(x, stats, gamma1, beta1, hbuf, N * 16, invN);
    spconv<<<nb, 256, 0, stream>>>(hbuf, nbr, W1f, out1b, nullptr, nullptr, stats + 256, N);
    bn_relu_b16<<<768, 256, 0, stream>>>(out1b, stats + 256, gamma2, beta2, hbuf, N * 8, invN);
    spconv<<<nb, 256, 0, stream>>>(hbuf, nbr, W2f, nullptr, out, x, nullptr, N);
}